// Round 2
// baseline (117.862 us; speedup 1.0000x reference)
//
#include <hip/hip_runtime.h>
#include <math.h>

#define N_  2
#define C_  128
#define H_  128
#define W_  128
#define G_  4
#define GC_ 32
#define P_  9
#define O_  72
#define WT  16      // pixels per block (along w)
#define X1S 129     // LDS stride for x1/out tile (conflict-free)
#define OFS 73      // LDS stride for per-pixel offsets

// LDS arena layout (bytes):
//   [0,     8256)  x1 tile   16*129*4      (phases A1-A3), reused as out tile (B/C)
//   [8256, 12928)  offs      16*73*4       (A3 -> A4)
//   [12928,17536)  desc_idx  576*8 (uint2) (A4 -> B)   [aliases red1/red2 in A1/A2]
//   [17536,26752)  desc_w    576*16(float4)(A4 -> B)
#define ARENA_BYTES 26752

__global__ __launch_bounds__(256, 6)
void dcn_fused(const float* __restrict__ inp,   // [N,C,H,W]
               const float* __restrict__ xin,   // [N,H,W,C]
               const float* __restrict__ dww,   // [3,3,1,C] HWIO
               const float* __restrict__ dwb,   // [C]
               const float* __restrict__ lng,   // [C]
               const float* __restrict__ lnb,   // [C]
               const float* __restrict__ offw,  // [72,C]
               const float* __restrict__ offb,  // [72]
               float* __restrict__ out)         // [N,C,H,W]
{
    __shared__ __align__(16) char arena[ARENA_BYTES];
    float*  x1     = (float*)arena;                  // 16 x 129
    float*  offs   = (float*)(arena + 8256);         // 16 x 73
    uint2*  desc_i = (uint2*)(arena + 12928);        // 576
    float4* desc_w = (float4*)(arena + 17536);       // 576
    float*  red1   = (float*)(arena + 12928);        // 16 x 16 (A1/A2 only)
    float*  red2   = (float*)(arena + 13952);        // 16 x 16

    const int t   = threadIdx.x;
    const int bid = blockIdx.x;
    // XCD-aware bijective swizzle: 2048 blocks = 8 XCDs x 256 contiguous
    const int sw  = ((bid & 7) << 8) | (bid >> 3);
    const int wt  = sw & 7;                 // W/WT = 8
    const int h   = (sw >> 3) & (H_ - 1);
    const int n   = sw >> 10;
    const int w0  = wt * WT;

    // ---------- A1: depthwise 3x3 conv (+bias), per-pixel LN partial stats ----------
    {
        const int w = t & 15;
        const int q = t >> 4;                // 0..15, 8 channels each
        float s1 = 0.f, s2 = 0.f;
        const int wcb = w0 + w - 1;
        #pragma unroll
        for (int i = 0; i < 8; ++i) {
            const int c = q * 8 + i;
            float acc = dwb[c];
            #pragma unroll
            for (int r = 0; r < 3; ++r) {
                const int hr = h - 1 + r;
                const bool rv = (hr >= 0) && (hr < H_);
                const float* row = inp + (((size_t)n * C_ + c) * H_ + hr) * W_;
                #pragma unroll
                for (int s = 0; s < 3; ++s) {
                    const int wc = wcb + s;
                    const float v = (rv && wc >= 0 && wc < W_) ? row[wc] : 0.f;
                    acc = fmaf(v, dww[(r * 3 + s) * C_ + c], acc);
                }
            }
            x1[w * X1S + c] = acc;
            s1 += acc;
            s2 = fmaf(acc, acc, s2);
        }
        red1[q * 16 + w] = s1;
        red2[q * 16 + w] = s2;
    }
    __syncthreads();

    // ---------- A2: LayerNorm + exact GELU (in place) ----------
    {
        const int w = t & 15;
        const int q = t >> 4;
        float s1 = 0.f, s2 = 0.f;
        #pragma unroll
        for (int j = 0; j < 16; ++j) { s1 += red1[j * 16 + w]; s2 += red2[j * 16 + w]; }
        const float mean = s1 * (1.f / 128.f);
        const float var  = s2 * (1.f / 128.f) - mean * mean;
        const float rstd = rsqrtf(var + 1e-6f);
        #pragma unroll
        for (int i = 0; i < 8; ++i) {
            const int c = q * 8 + i;
            float v = x1[w * X1S + c];
            v = (v - mean) * rstd * lng[c] + lnb[c];
            v = 0.5f * v * (1.f + erff(v * 0.70710678118654752440f));  // exact gelu
            x1[w * X1S + c] = v;
        }
    }
    __syncthreads();

    // ---------- A3: offset linear  off[o] = sum_c x1[c]*W[o,c] + b[o] ----------
    if (t < 128) {
        const int pix = t & 15;
        const int s   = t >> 4;              // 0..7, 9 outputs each
        float acc[9];
        #pragma unroll
        for (int o = 0; o < 9; ++o) acc[o] = offb[s * 9 + o];
        #pragma unroll 1
        for (int cb = 0; cb < C_; cb += 8) {
            float xv[8];
            #pragma unroll
            for (int k = 0; k < 8; ++k) xv[k] = x1[pix * X1S + cb + k];
            #pragma unroll
            for (int o = 0; o < 9; ++o) {
                const float4* wp = reinterpret_cast<const float4*>(&offw[(s * 9 + o) * C_ + cb]);
                const float4 wa = wp[0];
                const float4 wb = wp[1];
                acc[o] = fmaf(xv[0], wa.x, acc[o]);
                acc[o] = fmaf(xv[1], wa.y, acc[o]);
                acc[o] = fmaf(xv[2], wa.z, acc[o]);
                acc[o] = fmaf(xv[3], wa.w, acc[o]);
                acc[o] = fmaf(xv[4], wb.x, acc[o]);
                acc[o] = fmaf(xv[5], wb.y, acc[o]);
                acc[o] = fmaf(xv[6], wb.z, acc[o]);
                acc[o] = fmaf(xv[7], wb.w, acc[o]);
            }
        }
        #pragma unroll
        for (int o = 0; o < 9; ++o) offs[pix * OFS + s * 9 + o] = acc[o];
    }
    __syncthreads();

    // ---------- A4: per-tap bilinear descriptors (indices + weights) ----------
    // tap = (pix*4+g)*9 + p ; iy = h + p%3 + oy ; ix = w0+pix + p/3 + ox (padded coords)
    // corner (yy,xx) contributes x[yy-1,xx-1] iff 1<=yy<=H && 1<=xx<=W, else 0.
    {
        for (int tap = t; tap < WT * G_ * P_; tap += 256) {
            const int pg  = tap / 9;
            const int p   = tap - pg * 9;
            const int pix = pg >> 2;
            const int g   = pg & 3;
            const float ox = offs[pix * OFS + g * 18 + 2 * p];
            const float oy = offs[pix * OFS + g * 18 + 2 * p + 1];
            const float fy = (float)(h + (p % 3)) + oy;
            const float fx = (float)(w0 + pix + (p / 3)) + ox;
            const float y0f = floorf(fy);
            const float x0f = floorf(fx);
            const float wy = fy - y0f;
            const float wx = fx - x0f;
            const int y0 = (int)y0f;
            const int x0 = (int)x0f;
            const int yc0 = min(max(y0, 1), H_) - 1;
            const int yc1 = min(max(y0 + 1, 1), H_) - 1;
            const int xc0 = min(max(x0, 1), W_) - 1;
            const int xc1 = min(max(x0 + 1, 1), W_) - 1;
            const float a0 = (1.f - wy) * ((y0 >= 1 && y0 <= H_) ? 1.f : 0.f);
            const float a1 = wy * ((y0 + 1 >= 1 && y0 + 1 <= H_) ? 1.f : 0.f);
            const float b0 = (1.f - wx) * ((x0 >= 1 && x0 <= W_) ? 1.f : 0.f);
            const float b1 = wx * ((x0 + 1 >= 1 && x0 + 1 <= W_) ? 1.f : 0.f);
            desc_i[tap] = make_uint2(
                (uint32_t)(yc0 * W_ + xc0) | ((uint32_t)(yc0 * W_ + xc1) << 16),
                (uint32_t)(yc1 * W_ + xc0) | ((uint32_t)(yc1 * W_ + xc1) << 16));
            desc_w[tap] = make_float4(a0 * b0, a0 * b1, a1 * b0, a1 * b1);
        }
    }
    __syncthreads();

    // ---------- B: gather + weighted sum (branch-free) ----------
    {
        const int cl   = t & 31;             // channel within group
        const int slot = t >> 5;             // 8 slots
        const float* xb = xin + (size_t)n * (H_ * W_ * C_) + cl;
        #pragma unroll 1
        for (int it = 0; it < 8; ++it) {
            const int pair = it * 8 + slot;  // 0..63 = pix*4+g
            const int pix  = pair >> 2;
            const int g    = pair & 3;
            const float* xg = xb + g * GC_;
            const uint2*  di = &desc_i[pair * 9];
            const float4* dw = &desc_w[pair * 9];
            float acc = 0.f;
            #pragma unroll
            for (int p = 0; p < P_; ++p) {
                const uint2  pk = di[p];
                const float4 wv = dw[p];
                acc = fmaf(wv.x, xg[(size_t)(pk.x & 0xFFFFu) * C_], acc);
                acc = fmaf(wv.y, xg[(size_t)(pk.x >> 16) * C_], acc);
                acc = fmaf(wv.z, xg[(size_t)(pk.y & 0xFFFFu) * C_], acc);
                acc = fmaf(wv.w, xg[(size_t)(pk.y >> 16) * C_], acc);
            }
            x1[pix * X1S + g * GC_ + cl] = acc;   // out staging
        }
    }
    __syncthreads();

    // ---------- C: coalesced NCHW write ----------
    {
        const int pix = t & 15;
        const int cq  = t >> 4;
        #pragma unroll
        for (int i = 0; i < 8; ++i) {
            const int c = cq * 8 + i;
            out[(((size_t)n * C_ + c) * H_ + h) * W_ + w0 + pix] = x1[pix * X1S + c];
        }
    }
}

extern "C" void kernel_launch(void* const* d_in, const int* in_sizes, int n_in,
                              void* d_out, int out_size, void* d_ws, size_t ws_size,
                              hipStream_t stream) {
    const float* inp  = (const float*)d_in[0];
    const float* xin  = (const float*)d_in[1];
    const float* dww  = (const float*)d_in[2];
    const float* dwb  = (const float*)d_in[3];
    const float* lng  = (const float*)d_in[4];
    const float* lnb  = (const float*)d_in[5];
    const float* offw = (const float*)d_in[6];
    const float* offb = (const float*)d_in[7];
    float* outp = (float*)d_out;

    const int blocks = N_ * H_ * (W_ / WT);   // 2048
    dcn_fused<<<dim3(blocks), dim3(256), 0, stream>>>(
        inp, xin, dww, dwb, lng, lnb, offw, offb, outp);
}

// Round 3
// 97.269 us; speedup vs baseline: 1.2117x; 1.2117x over previous
//
#include <hip/hip_runtime.h>
#include <hip/hip_fp16.h>
#include <math.h>

#define N_  2
#define C_  128
#define H_  128
#define W_  128
#define G_  4
#define GC_ 32
#define P_  9
#define WT  16      // pixels per block (along w)
#define X1S 132     // x1/out tile stride (floats): 132%32=4 -> 2-way max, 16B aligned rows
#define OFS 73      // offs stride (floats)

// LDS arena (bytes):
//   [0,     8448)  x1 tile 16*132*4        (A1-A3), reused as out staging (B/C)
//   [8448, 17664)  desc4   576*16 (uint4)  (A4 -> B)  [aliases red1/red2 in A1/A2]
//   [17664,22336)  offs    16*73*4         (A3 -> A4)
#define ARENA_BYTES 22336

union HU { __half h; unsigned short u; };
static __device__ __forceinline__ unsigned int f2h(float f) {
    HU x; x.h = __float2half(f); return (unsigned int)x.u;
}
static __device__ __forceinline__ float h2f(unsigned int v) {
    HU x; x.u = (unsigned short)v; return __half2float(x.h);
}

__global__ __launch_bounds__(256, 6)
void dcn_fused(const float* __restrict__ inp,   // [N,C,H,W]
               const float* __restrict__ xin,   // [N,H,W,C]
               const float* __restrict__ dww,   // [3,3,1,C] HWIO
               const float* __restrict__ dwb,   // [C]
               const float* __restrict__ lng,   // [C]
               const float* __restrict__ lnb,   // [C]
               const float* __restrict__ offw,  // [72,C]
               const float* __restrict__ offb,  // [72]
               float* __restrict__ out)         // [N,C,H,W]
{
    __shared__ __align__(16) char arena[ARENA_BYTES];
    float*  x1     = (float*)arena;                  // 16 x 132
    uint4*  desc4  = (uint4*)(arena + 8448);         // 576 taps
    float*  red1   = (float*)(arena + 8448);         // 16x16 (A1/A2 only)
    float*  red2   = (float*)(arena + 9472);
    float*  offs   = (float*)(arena + 17664);        // 16 x 73

    const int t   = threadIdx.x;
    const int bid = blockIdx.x;
    // XCD-aware bijective swizzle: 2048 = 8 XCDs x 256
    const int sw  = ((bid & 7) << 8) | (bid >> 3);
    const int wt  = sw & 7;
    const int h   = (sw >> 3) & (H_ - 1);
    const int n   = sw >> 10;
    const int w0  = wt * WT;

    // ---------- A1: depthwise 3x3 conv (+bias), LN partial stats ----------
    {
        const int w = t & 15;
        const int q = t >> 4;                // 16 c-groups of 8
        float s1 = 0.f, s2 = 0.f;
        const int wcb = w0 + w - 1;
        #pragma unroll
        for (int i = 0; i < 8; ++i) {
            const int c = q * 8 + i;
            float acc = dwb[c];
            #pragma unroll
            for (int r = 0; r < 3; ++r) {
                const int hr = h - 1 + r;
                const bool rv = (hr >= 0) && (hr < H_);
                const float* row = inp + (((size_t)n * C_ + c) * H_ + hr) * W_;
                #pragma unroll
                for (int s = 0; s < 3; ++s) {
                    const int wc = wcb + s;
                    const float v = (rv && wc >= 0 && wc < W_) ? row[wc] : 0.f;
                    acc = fmaf(v, dww[(r * 3 + s) * C_ + c], acc);
                }
            }
            x1[w * X1S + c] = acc;
            s1 += acc;
            s2 = fmaf(acc, acc, s2);
        }
        red1[q * 16 + w] = s1;
        red2[q * 16 + w] = s2;
    }
    __syncthreads();

    // ---------- A2: LayerNorm + exact GELU (in place) ----------
    {
        const int w = t & 15;
        const int q = t >> 4;
        float s1 = 0.f, s2 = 0.f;
        #pragma unroll
        for (int j = 0; j < 16; ++j) { s1 += red1[j * 16 + w]; s2 += red2[j * 16 + w]; }
        const float mean = s1 * (1.f / 128.f);
        const float var  = s2 * (1.f / 128.f) - mean * mean;
        const float rstd = rsqrtf(var + 1e-6f);
        #pragma unroll
        for (int i = 0; i < 8; ++i) {
            const int c = q * 8 + i;
            float v = x1[w * X1S + c];
            v = (v - mean) * rstd * lng[c] + lnb[c];
            v = 0.5f * v * (1.f + erff(v * 0.70710678118654752440f));
            x1[w * X1S + c] = v;
        }
    }
    __syncthreads();

    // ---------- A3: offset linear, all 256 threads (4.5 outputs each) ----------
    {
        const int pix  = t & 15;
        const int s    = t >> 4;             // 0..15  (wave-uniform has5)
        const bool has5 = (s < 8);
        float acc[5];
        #pragma unroll
        for (int j = 0; j < 4; ++j) acc[j] = offb[s * 4 + j];
        acc[4] = has5 ? offb[64 + s] : 0.f;
        #pragma unroll 1
        for (int cb = 0; cb < C_; cb += 8) {
            const float4 xa = *(const float4*)&x1[pix * X1S + cb];
            const float4 xb = *(const float4*)&x1[pix * X1S + cb + 4];
            #pragma unroll
            for (int j = 0; j < 4; ++j) {
                const int o = s * 4 + j;
                const float4 wa = *(const float4*)&offw[o * C_ + cb];
                const float4 wb = *(const float4*)&offw[o * C_ + cb + 4];
                acc[j] = fmaf(xa.x, wa.x, acc[j]);
                acc[j] = fmaf(xa.y, wa.y, acc[j]);
                acc[j] = fmaf(xa.z, wa.z, acc[j]);
                acc[j] = fmaf(xa.w, wa.w, acc[j]);
                acc[j] = fmaf(xb.x, wb.x, acc[j]);
                acc[j] = fmaf(xb.y, wb.y, acc[j]);
                acc[j] = fmaf(xb.z, wb.z, acc[j]);
                acc[j] = fmaf(xb.w, wb.w, acc[j]);
            }
            if (has5) {
                const int o = 64 + s;
                const float4 wa = *(const float4*)&offw[o * C_ + cb];
                const float4 wb = *(const float4*)&offw[o * C_ + cb + 4];
                acc[4] = fmaf(xa.x, wa.x, acc[4]);
                acc[4] = fmaf(xa.y, wa.y, acc[4]);
                acc[4] = fmaf(xa.z, wa.z, acc[4]);
                acc[4] = fmaf(xa.w, wa.w, acc[4]);
                acc[4] = fmaf(xb.x, wb.x, acc[4]);
                acc[4] = fmaf(xb.y, wb.y, acc[4]);
                acc[4] = fmaf(xb.z, wb.z, acc[4]);
                acc[4] = fmaf(xb.w, wb.w, acc[4]);
            }
        }
        #pragma unroll
        for (int j = 0; j < 4; ++j) offs[pix * OFS + s * 4 + j] = acc[j];
        if (has5) offs[pix * OFS + 64 + s] = acc[4];
    }
    __syncthreads();

    // ---------- A4: per-tap packed descriptor: 4 x u16 idx + 4 x f16 weights ----------
    {
        for (int tap = t; tap < WT * G_ * P_; tap += 256) {
            const int pg  = tap / 9;
            const int p   = tap - pg * 9;
            const int pix = pg >> 2;
            const int g   = pg & 3;
            const float ox = offs[pix * OFS + g * 18 + 2 * p];
            const float oy = offs[pix * OFS + g * 18 + 2 * p + 1];
            const float fy = (float)(h + (p % 3)) + oy;
            const float fx = (float)(w0 + pix + (p / 3)) + ox;
            const float y0f = floorf(fy);
            const float x0f = floorf(fx);
            const float wy = fy - y0f;
            const float wx = fx - x0f;
            const int y0 = (int)y0f;
            const int x0 = (int)x0f;
            const int yc0 = min(max(y0, 1), H_) - 1;
            const int yc1 = min(max(y0 + 1, 1), H_) - 1;
            const int xc0 = min(max(x0, 1), W_) - 1;
            const int xc1 = min(max(x0 + 1, 1), W_) - 1;
            const float a0 = (1.f - wy) * ((y0 >= 1 && y0 <= H_) ? 1.f : 0.f);
            const float a1 = wy * ((y0 + 1 >= 1 && y0 + 1 <= H_) ? 1.f : 0.f);
            const float b0 = (1.f - wx) * ((x0 >= 1 && x0 <= W_) ? 1.f : 0.f);
            const float b1 = wx * ((x0 + 1 >= 1 && x0 + 1 <= W_) ? 1.f : 0.f);
            const unsigned int i00 = (unsigned int)(yc0 * W_ + xc0);
            const unsigned int i01 = (unsigned int)(yc0 * W_ + xc1);
            const unsigned int i10 = (unsigned int)(yc1 * W_ + xc0);
            const unsigned int i11 = (unsigned int)(yc1 * W_ + xc1);
            desc4[tap] = make_uint4(i00 | (i01 << 16),
                                    i10 | (i11 << 16),
                                    f2h(a0 * b0) | (f2h(a0 * b1) << 16),
                                    f2h(a1 * b0) | (f2h(a1 * b1) << 16));
        }
    }
    __syncthreads();

    // ---------- B: gather, float2 channels, 2 pairs/thread for ILP ----------
    {
        const int k    = t & 15;             // channel-pair within group
        const int slot = t >> 4;             // 16 slots
        const float2* xb2 = (const float2*)xin + (size_t)n * (H_ * W_ * C_ / 2) + k;
        float2* st = (float2*)x1;            // stride X1S/2 = 66
        #pragma unroll 1
        for (int it = 0; it < 2; ++it) {
            const int pairA = it * 32 + slot;
            const int pairB = pairA + 16;
            const int pixA = pairA >> 2, gA = pairA & 3;
            const int pixB = pairB >> 2, gB = pairB & 3;
            const float2* xgA = xb2 + gA * (GC_ / 2);
            const float2* xgB = xb2 + gB * (GC_ / 2);
            const uint4* dAp = desc4 + pairA * 9;
            const uint4* dBp = desc4 + pairB * 9;
            float aAx = 0.f, aAy = 0.f, aBx = 0.f, aBy = 0.f;
            #pragma unroll
            for (int p = 0; p < P_; ++p) {
                const uint4 da = dAp[p];
                const uint4 db = dBp[p];
                const float2 vA00 = xgA[(da.x & 0xFFFFu) * 64u];
                const float2 vA01 = xgA[(da.x >> 16) * 64u];
                const float2 vA10 = xgA[(da.y & 0xFFFFu) * 64u];
                const float2 vA11 = xgA[(da.y >> 16) * 64u];
                const float2 vB00 = xgB[(db.x & 0xFFFFu) * 64u];
                const float2 vB01 = xgB[(db.x >> 16) * 64u];
                const float2 vB10 = xgB[(db.y & 0xFFFFu) * 64u];
                const float2 vB11 = xgB[(db.y >> 16) * 64u];
                const float wA00 = h2f(da.z & 0xFFFFu), wA01 = h2f(da.z >> 16);
                const float wA10 = h2f(da.w & 0xFFFFu), wA11 = h2f(da.w >> 16);
                const float wB00 = h2f(db.z & 0xFFFFu), wB01 = h2f(db.z >> 16);
                const float wB10 = h2f(db.w & 0xFFFFu), wB11 = h2f(db.w >> 16);
                aAx = fmaf(wA00, vA00.x, aAx); aAy = fmaf(wA00, vA00.y, aAy);
                aAx = fmaf(wA01, vA01.x, aAx); aAy = fmaf(wA01, vA01.y, aAy);
                aAx = fmaf(wA10, vA10.x, aAx); aAy = fmaf(wA10, vA10.y, aAy);
                aAx = fmaf(wA11, vA11.x, aAx); aAy = fmaf(wA11, vA11.y, aAy);
                aBx = fmaf(wB00, vB00.x, aBx); aBy = fmaf(wB00, vB00.y, aBy);
                aBx = fmaf(wB01, vB01.x, aBx); aBy = fmaf(wB01, vB01.y, aBy);
                aBx = fmaf(wB10, vB10.x, aBx); aBy = fmaf(wB10, vB10.y, aBy);
                aBx = fmaf(wB11, vB11.x, aBx); aBy = fmaf(wB11, vB11.y, aBy);
            }
            st[pixA * (X1S / 2) + gA * (GC_ / 2) + k] = make_float2(aAx, aAy);
            st[pixB * (X1S / 2) + gB * (GC_ / 2) + k] = make_float2(aBx, aBy);
        }
    }
    __syncthreads();

    // ---------- C: coalesced NCHW write ----------
    {
        const int pix = t & 15;
        const int cq  = t >> 4;
        #pragma unroll
        for (int i = 0; i < 8; ++i) {
            const int c = cq * 8 + i;
            out[(((size_t)n * C_ + c) * H_ + h) * W_ + w0 + pix] = x1[pix * X1S + c];
        }
    }
}

extern "C" void kernel_launch(void* const* d_in, const int* in_sizes, int n_in,
                              void* d_out, int out_size, void* d_ws, size_t ws_size,
                              hipStream_t stream) {
    const float* inp  = (const float*)d_in[0];
    const float* xin  = (const float*)d_in[1];
    const float* dww  = (const float*)d_in[2];
    const float* dwb  = (const float*)d_in[3];
    const float* lng  = (const float*)d_in[4];
    const float* lnb  = (const float*)d_in[5];
    const float* offw = (const float*)d_in[6];
    const float* offb = (const float*)d_in[7];
    float* outp = (float*)d_out;

    const int blocks = N_ * H_ * (W_ / WT);   // 2048
    dcn_fused<<<dim3(blocks), dim3(256), 0, stream>>>(
        inp, xin, dww, dwb, lng, lnb, offw, offb, outp);
}

// Round 4
// 79.414 us; speedup vs baseline: 1.4841x; 1.2248x over previous
//
#include <hip/hip_runtime.h>
#include <hip/hip_fp16.h>
#include <math.h>

#define N_  2
#define C_  128
#define H_  128
#define W_  128
#define G_  4
#define GC_ 32
#define P_  9
#define WT  16      // pixels per block (along w)
#define X1S 132     // x1/out tile stride (floats)
#define OFS 73      // offs stride (floats)

#define DESC_BYTES ((size_t)N_ * H_ * W_ * G_ * P_ * 16)   // 18.9 MB

union HU { __half h; unsigned short u; };
static __device__ __forceinline__ unsigned int f2h(float f) {
    HU x; x.h = __float2half(f); return (unsigned int)x.u;
}
static __device__ __forceinline__ float h2f(unsigned int v) {
    HU x; x.u = (unsigned short)v; return __half2float(x.h);
}

// ===================== K1: dw-conv -> LN -> GELU -> offset linear -> descriptors =====================
// LDS: x1 16*132*4 = 8448 ; offs 16*73*4 = 4672 (red1/red2 alias offs region in A1/A2)
#define K1_ARENA (8448 + 4672)

__global__ __launch_bounds__(256, 8)
void dcn_stage1(const float* __restrict__ inp,   // [N,C,H,W]
                const float* __restrict__ dww,   // [3,3,1,C]
                const float* __restrict__ dwb,   // [C]
                const float* __restrict__ lng,   // [C]
                const float* __restrict__ lnb,   // [C]
                const float* __restrict__ offw,  // [72,C]
                const float* __restrict__ offb,  // [72]
                uint4* __restrict__ desc)        // [N*H*W, 36]
{
    __shared__ __align__(16) char arena[K1_ARENA];
    float* x1   = (float*)arena;                 // 16 x 132
    float* offs = (float*)(arena + 8448);        // 16 x 73
    float* red1 = (float*)(arena + 8448);        // 16x16 (A1/A2 only, alias)
    float* red2 = (float*)(arena + 9472);

    const int t   = threadIdx.x;
    const int bid = blockIdx.x;
    const int sw  = ((bid & 7) << 8) | (bid >> 3);   // XCD swizzle (2048 = 8*256)
    const int wt  = sw & 7;
    const int h   = (sw >> 3) & (H_ - 1);
    const int n   = sw >> 10;
    const int w0  = wt * WT;
    const int pixbase = (n * H_ + h) * W_ + w0;

    // ---------- A1: depthwise 3x3 conv (+bias), LN partial stats ----------
    {
        const int w = t & 15;
        const int q = t >> 4;
        float s1 = 0.f, s2 = 0.f;
        const int wcb = w0 + w - 1;
        #pragma unroll
        for (int i = 0; i < 8; ++i) {
            const int c = q * 8 + i;
            float acc = dwb[c];
            #pragma unroll
            for (int r = 0; r < 3; ++r) {
                const int hr = h - 1 + r;
                const bool rv = (hr >= 0) && (hr < H_);
                const float* row = inp + (((size_t)n * C_ + c) * H_ + hr) * W_;
                #pragma unroll
                for (int s = 0; s < 3; ++s) {
                    const int wc = wcb + s;
                    const float v = (rv && wc >= 0 && wc < W_) ? row[wc] : 0.f;
                    acc = fmaf(v, dww[(r * 3 + s) * C_ + c], acc);
                }
            }
            x1[w * X1S + c] = acc;
            s1 += acc;
            s2 = fmaf(acc, acc, s2);
        }
        red1[q * 16 + w] = s1;
        red2[q * 16 + w] = s2;
    }
    __syncthreads();

    // ---------- A2: LayerNorm + exact GELU ----------
    {
        const int w = t & 15;
        const int q = t >> 4;
        float s1 = 0.f, s2 = 0.f;
        #pragma unroll
        for (int j = 0; j < 16; ++j) { s1 += red1[j * 16 + w]; s2 += red2[j * 16 + w]; }
        const float mean = s1 * (1.f / 128.f);
        const float var  = s2 * (1.f / 128.f) - mean * mean;
        const float rstd = rsqrtf(var + 1e-6f);
        #pragma unroll
        for (int i = 0; i < 8; ++i) {
            const int c = q * 8 + i;
            float v = x1[w * X1S + c];
            v = (v - mean) * rstd * lng[c] + lnb[c];
            v = 0.5f * v * (1.f + erff(v * 0.70710678118654752440f));
            x1[w * X1S + c] = v;
        }
    }
    __syncthreads();

    // ---------- A3: offset linear ----------
    {
        const int pix  = t & 15;
        const int s    = t >> 4;
        const bool has5 = (s < 8);
        float acc[5];
        #pragma unroll
        for (int j = 0; j < 4; ++j) acc[j] = offb[s * 4 + j];
        acc[4] = has5 ? offb[64 + s] : 0.f;
        #pragma unroll 1
        for (int cb = 0; cb < C_; cb += 8) {
            const float4 xa = *(const float4*)&x1[pix * X1S + cb];
            const float4 xb = *(const float4*)&x1[pix * X1S + cb + 4];
            #pragma unroll
            for (int j = 0; j < 4; ++j) {
                const int o = s * 4 + j;
                const float4 wa = *(const float4*)&offw[o * C_ + cb];
                const float4 wb = *(const float4*)&offw[o * C_ + cb + 4];
                acc[j] = fmaf(xa.x, wa.x, acc[j]);
                acc[j] = fmaf(xa.y, wa.y, acc[j]);
                acc[j] = fmaf(xa.z, wa.z, acc[j]);
                acc[j] = fmaf(xa.w, wa.w, acc[j]);
                acc[j] = fmaf(xb.x, wb.x, acc[j]);
                acc[j] = fmaf(xb.y, wb.y, acc[j]);
                acc[j] = fmaf(xb.z, wb.z, acc[j]);
                acc[j] = fmaf(xb.w, wb.w, acc[j]);
            }
            if (has5) {
                const int o = 64 + s;
                const float4 wa = *(const float4*)&offw[o * C_ + cb];
                const float4 wb = *(const float4*)&offw[o * C_ + cb + 4];
                acc[4] = fmaf(xa.x, wa.x, acc[4]);
                acc[4] = fmaf(xa.y, wa.y, acc[4]);
                acc[4] = fmaf(xa.z, wa.z, acc[4]);
                acc[4] = fmaf(xa.w, wa.w, acc[4]);
                acc[4] = fmaf(xb.x, wb.x, acc[4]);
                acc[4] = fmaf(xb.y, wb.y, acc[4]);
                acc[4] = fmaf(xb.z, wb.z, acc[4]);
                acc[4] = fmaf(xb.w, wb.w, acc[4]);
            }
        }
        #pragma unroll
        for (int j = 0; j < 4; ++j) offs[pix * OFS + s * 4 + j] = acc[j];
        if (has5) offs[pix * OFS + 64 + s] = acc[4];
    }
    __syncthreads();

    // ---------- A4: pack per-tap descriptor -> global (coalesced 16B stream) ----------
    {
        for (int tap = t; tap < WT * G_ * P_; tap += 256) {
            const int pg  = tap / 9;
            const int p   = tap - pg * 9;
            const int pix = pg >> 2;
            const int g   = pg & 3;
            const float ox = offs[pix * OFS + g * 18 + 2 * p];
            const float oy = offs[pix * OFS + g * 18 + 2 * p + 1];
            const float fy = (float)(h + (p % 3)) + oy;
            const float fx = (float)(w0 + pix + (p / 3)) + ox;
            const float y0f = floorf(fy);
            const float x0f = floorf(fx);
            const float wy = fy - y0f;
            const float wx = fx - x0f;
            const int y0 = (int)y0f;
            const int x0 = (int)x0f;
            const int yc0 = min(max(y0, 1), H_) - 1;
            const int yc1 = min(max(y0 + 1, 1), H_) - 1;
            const int xc0 = min(max(x0, 1), W_) - 1;
            const int xc1 = min(max(x0 + 1, 1), W_) - 1;
            const float a0 = (1.f - wy) * ((y0 >= 1 && y0 <= H_) ? 1.f : 0.f);
            const float a1 = wy * ((y0 + 1 >= 1 && y0 + 1 <= H_) ? 1.f : 0.f);
            const float b0 = (1.f - wx) * ((x0 >= 1 && x0 <= W_) ? 1.f : 0.f);
            const float b1 = wx * ((x0 + 1 >= 1 && x0 + 1 <= W_) ? 1.f : 0.f);
            const unsigned int i00 = (unsigned int)(yc0 * W_ + xc0);
            const unsigned int i01 = (unsigned int)(yc0 * W_ + xc1);
            const unsigned int i10 = (unsigned int)(yc1 * W_ + xc0);
            const unsigned int i11 = (unsigned int)(yc1 * W_ + xc1);
            desc[(size_t)pixbase * 36 + tap] =
                make_uint4(i00 | (i01 << 16),
                           i10 | (i11 << 16),
                           f2h(a0 * b0) | (f2h(a0 * b1) << 16),
                           f2h(a1 * b0) | (f2h(a1 * b1) << 16));
        }
    }
}

// ===================== K2: pure gather (no inter-phase barriers, deep ILP) =====================
__global__ __launch_bounds__(512, 4)
void dcn_gather(const float* __restrict__ xin,   // [N,H,W,C]
                const uint4* __restrict__ desc,  // [N*H*W, 36]
                float* __restrict__ out)         // [N,C,H,W]
{
    __shared__ __align__(16) float stage[WT * X1S];   // 16 x 132

    const int t   = threadIdx.x;
    const int bid = blockIdx.x;
    const int sw  = ((bid & 7) << 8) | (bid >> 3);    // same XCD swizzle as K1
    const int wt  = sw & 7;
    const int h   = (sw >> 3) & (H_ - 1);
    const int n   = sw >> 10;
    const int w0  = wt * WT;
    const int pixbase = (n * H_ + h) * W_ + w0;

    {
        const int k   = t & 7;        // channel quad within group
        const int pl  = t >> 3;       // 0..63 = pix*4+g
        const int pix = pl >> 2;
        const int g   = pl & 3;
        const uint4* dp = desc + (size_t)(pixbase + pix) * 36 + g * 9;
        const float4* xg = (const float4*)xin + (size_t)n * (H_ * W_ * (C_ / 4)) + g * (GC_ / 4) + k;

        uint4 d[9];
        #pragma unroll
        for (int p = 0; p < P_; ++p) d[p] = dp[p];

        float4 acc = make_float4(0.f, 0.f, 0.f, 0.f);
        #pragma unroll
        for (int p = 0; p < P_; ++p) {
            const float4 v00 = xg[(d[p].x & 0xFFFFu) * 32u];
            const float4 v01 = xg[(d[p].x >> 16) * 32u];
            const float4 v10 = xg[(d[p].y & 0xFFFFu) * 32u];
            const float4 v11 = xg[(d[p].y >> 16) * 32u];
            const float w00 = h2f(d[p].z & 0xFFFFu), w01 = h2f(d[p].z >> 16);
            const float w10 = h2f(d[p].w & 0xFFFFu), w11 = h2f(d[p].w >> 16);
            acc.x = fmaf(w00, v00.x, acc.x);
            acc.y = fmaf(w00, v00.y, acc.y);
            acc.z = fmaf(w00, v00.z, acc.z);
            acc.w = fmaf(w00, v00.w, acc.w);
            acc.x = fmaf(w01, v01.x, acc.x);
            acc.y = fmaf(w01, v01.y, acc.y);
            acc.z = fmaf(w01, v01.z, acc.z);
            acc.w = fmaf(w01, v01.w, acc.w);
            acc.x = fmaf(w10, v10.x, acc.x);
            acc.y = fmaf(w10, v10.y, acc.y);
            acc.z = fmaf(w10, v10.z, acc.z);
            acc.w = fmaf(w10, v10.w, acc.w);
            acc.x = fmaf(w11, v11.x, acc.x);
            acc.y = fmaf(w11, v11.y, acc.y);
            acc.z = fmaf(w11, v11.z, acc.z);
            acc.w = fmaf(w11, v11.w, acc.w);
        }
        *(float4*)&stage[pix * X1S + g * GC_ + k * 4] = acc;
    }
    __syncthreads();

    // transpose write: NCHW, 64B segments per c-plane
    {
        const int pix = t & 15;
        const int c0  = t >> 4;       // 0..31
        #pragma unroll
        for (int i = 0; i < 4; ++i) {
            const int c = c0 + 32 * i;
            out[(((size_t)n * C_ + c) * H_ + h) * W_ + w0 + pix] = stage[pix * X1S + c];
        }
    }
}

// ===================== fallback: monolithic (R3) if ws too small =====================
#define ARENA_BYTES 22336
__global__ __launch_bounds__(256, 6)
void dcn_fused_mono(const float* __restrict__ inp, const float* __restrict__ xin,
                    const float* __restrict__ dww, const float* __restrict__ dwb,
                    const float* __restrict__ lng, const float* __restrict__ lnb,
                    const float* __restrict__ offw, const float* __restrict__ offb,
                    float* __restrict__ out)
{
    __shared__ __align__(16) char arena[ARENA_BYTES];
    float*  x1     = (float*)arena;
    uint4*  desc4  = (uint4*)(arena + 8448);
    float*  red1   = (float*)(arena + 8448);
    float*  red2   = (float*)(arena + 9472);
    float*  offs   = (float*)(arena + 17664);

    const int t   = threadIdx.x;
    const int bid = blockIdx.x;
    const int sw  = ((bid & 7) << 8) | (bid >> 3);
    const int wt  = sw & 7;
    const int h   = (sw >> 3) & (H_ - 1);
    const int n   = sw >> 10;
    const int w0  = wt * WT;

    {
        const int w = t & 15;
        const int q = t >> 4;
        float s1 = 0.f, s2 = 0.f;
        const int wcb = w0 + w - 1;
        #pragma unroll
        for (int i = 0; i < 8; ++i) {
            const int c = q * 8 + i;
            float acc = dwb[c];
            #pragma unroll
            for (int r = 0; r < 3; ++r) {
                const int hr = h - 1 + r;
                const bool rv = (hr >= 0) && (hr < H_);
                const float* row = inp + (((size_t)n * C_ + c) * H_ + hr) * W_;
                #pragma unroll
                for (int s = 0; s < 3; ++s) {
                    const int wc = wcb + s;
                    const float v = (rv && wc >= 0 && wc < W_) ? row[wc] : 0.f;
                    acc = fmaf(v, dww[(r * 3 + s) * C_ + c], acc);
                }
            }
            x1[w * X1S + c] = acc;
            s1 += acc;
            s2 = fmaf(acc, acc, s2);
        }
        red1[q * 16 + w] = s1;
        red2[q * 16 + w] = s2;
    }
    __syncthreads();
    {
        const int w = t & 15;
        const int q = t >> 4;
        float s1 = 0.f, s2 = 0.f;
        #pragma unroll
        for (int j = 0; j < 16; ++j) { s1 += red1[j * 16 + w]; s2 += red2[j * 16 + w]; }
        const float mean = s1 * (1.f / 128.f);
        const float var  = s2 * (1.f / 128.f) - mean * mean;
        const float rstd = rsqrtf(var + 1e-6f);
        #pragma unroll
        for (int i = 0; i < 8; ++i) {
            const int c = q * 8 + i;
            float v = x1[w * X1S + c];
            v = (v - mean) * rstd * lng[c] + lnb[c];
            v = 0.5f * v * (1.f + erff(v * 0.70710678118654752440f));
            x1[w * X1S + c] = v;
        }
    }
    __syncthreads();
    {
        const int pix  = t & 15;
        const int s    = t >> 4;
        const bool has5 = (s < 8);
        float acc[5];
        #pragma unroll
        for (int j = 0; j < 4; ++j) acc[j] = offb[s * 4 + j];
        acc[4] = has5 ? offb[64 + s] : 0.f;
        #pragma unroll 1
        for (int cb = 0; cb < C_; cb += 8) {
            const float4 xa = *(const float4*)&x1[pix * X1S + cb];
            const float4 xb = *(const float4*)&x1[pix * X1S + cb + 4];
            #pragma unroll
            for (int j = 0; j < 4; ++j) {
                const int o = s * 4 + j;
                const float4 wa = *(const float4*)&offw[o * C_ + cb];
                const float4 wb = *(const float4*)&offw[o * C_ + cb + 4];
                acc[j] = fmaf(xa.x, wa.x, acc[j]);
                acc[j] = fmaf(xa.y, wa.y, acc[j]);
                acc[j] = fmaf(xa.z, wa.z, acc[j]);
                acc[j] = fmaf(xa.w, wa.w, acc[j]);
                acc[j] = fmaf(xb.x, wb.x, acc[j]);
                acc[j] = fmaf(xb.y, wb.y, acc[j]);
                acc[j] = fmaf(xb.z, wb.z, acc[j]);
                acc[j] = fmaf(xb.w, wb.w, acc[j]);
            }
            if (has5) {
                const int o = 64 + s;
                const float4 wa = *(const float4*)&offw[o * C_ + cb];
                const float4 wb = *(const float4*)&offw[o * C_ + cb + 4];
                acc[4] = fmaf(xa.x, wa.x, acc[4]);
                acc[4] = fmaf(xa.y, wa.y, acc[4]);
                acc[4] = fmaf(xa.z, wa.z, acc[4]);
                acc[4] = fmaf(xa.w, wa.w, acc[4]);
                acc[4] = fmaf(xb.x, wb.x, acc[4]);
                acc[4] = fmaf(xb.y, wb.y, acc[4]);
                acc[4] = fmaf(xb.z, wb.z, acc[4]);
                acc[4] = fmaf(xb.w, wb.w, acc[4]);
            }
        }
        #pragma unroll
        for (int j = 0; j < 4; ++j) offs[pix * OFS + s * 4 + j] = acc[j];
        if (has5) offs[pix * OFS + 64 + s] = acc[4];
    }
    __syncthreads();
    {
        for (int tap = t; tap < WT * G_ * P_; tap += 256) {
            const int pg  = tap / 9;
            const int p   = tap - pg * 9;
            const int pix = pg >> 2;
            const int g   = pg & 3;
            const float ox = offs[pix * OFS + g * 18 + 2 * p];
            const float oy = offs[pix * OFS + g * 18 + 2 * p + 1];
            const float fy = (float)(h + (p % 3)) + oy;
            const float fx = (float)(w0 + pix + (p / 3)) + ox;
            const float y0f = floorf(fy);
            const float x0f = floorf(fx);
            const float wy = fy - y0f;
            const float wx = fx - x0f;
            const int y0 = (int)y0f;
            const int x0 = (int)x0f;
            const int yc0 = min(max(y0, 1), H_) - 1;
            const int yc1 = min(max(y0 + 1, 1), H_) - 1;
            const int xc0 = min(max(x0, 1), W_) - 1;
            const int xc1 = min(max(x0 + 1, 1), W_) - 1;
            const float a0 = (1.f - wy) * ((y0 >= 1 && y0 <= H_) ? 1.f : 0.f);
            const float a1 = wy * ((y0 + 1 >= 1 && y0 + 1 <= H_) ? 1.f : 0.f);
            const float b0 = (1.f - wx) * ((x0 >= 1 && x0 <= W_) ? 1.f : 0.f);
            const float b1 = wx * ((x0 + 1 >= 1 && x0 + 1 <= W_) ? 1.f : 0.f);
            const unsigned int i00 = (unsigned int)(yc0 * W_ + xc0);
            const unsigned int i01 = (unsigned int)(yc0 * W_ + xc1);
            const unsigned int i10 = (unsigned int)(yc1 * W_ + xc0);
            const unsigned int i11 = (unsigned int)(yc1 * W_ + xc1);
            desc4[tap] = make_uint4(i00 | (i01 << 16),
                                    i10 | (i11 << 16),
                                    f2h(a0 * b0) | (f2h(a0 * b1) << 16),
                                    f2h(a1 * b0) | (f2h(a1 * b1) << 16));
        }
    }
    __syncthreads();
    {
        const int k    = t & 15;
        const int slot = t >> 4;
        const float2* xb2 = (const float2*)xin + (size_t)n * (H_ * W_ * C_ / 2) + k;
        float2* st = (float2*)x1;
        #pragma unroll 1
        for (int it = 0; it < 2; ++it) {
            const int pairA = it * 32 + slot;
            const int pairB = pairA + 16;
            const int pixA = pairA >> 2, gA = pairA & 3;
            const int pixB = pairB >> 2, gB = pairB & 3;
            const float2* xgA = xb2 + gA * (GC_ / 2);
            const float2* xgB = xb2 + gB * (GC_ / 2);
            const uint4* dAp = desc4 + pairA * 9;
            const uint4* dBp = desc4 + pairB * 9;
            float aAx = 0.f, aAy = 0.f, aBx = 0.f, aBy = 0.f;
            #pragma unroll
            for (int p = 0; p < P_; ++p) {
                const uint4 da = dAp[p];
                const uint4 db = dBp[p];
                const float2 vA00 = xgA[(da.x & 0xFFFFu) * 64u];
                const float2 vA01 = xgA[(da.x >> 16) * 64u];
                const float2 vA10 = xgA[(da.y & 0xFFFFu) * 64u];
                const float2 vA11 = xgA[(da.y >> 16) * 64u];
                const float2 vB00 = xgB[(db.x & 0xFFFFu) * 64u];
                const float2 vB01 = xgB[(db.x >> 16) * 64u];
                const float2 vB10 = xgB[(db.y & 0xFFFFu) * 64u];
                const float2 vB11 = xgB[(db.y >> 16) * 64u];
                const float wA00 = h2f(da.z & 0xFFFFu), wA01 = h2f(da.z >> 16);
                const float wA10 = h2f(da.w & 0xFFFFu), wA11 = h2f(da.w >> 16);
                const float wB00 = h2f(db.z & 0xFFFFu), wB01 = h2f(db.z >> 16);
                const float wB10 = h2f(db.w & 0xFFFFu), wB11 = h2f(db.w >> 16);
                aAx = fmaf(wA00, vA00.x, aAx); aAy = fmaf(wA00, vA00.y, aAy);
                aAx = fmaf(wA01, vA01.x, aAx); aAy = fmaf(wA01, vA01.y, aAy);
                aAx = fmaf(wA10, vA10.x, aAx); aAy = fmaf(wA10, vA10.y, aAy);
                aAx = fmaf(wA11, vA11.x, aAx); aAy = fmaf(wA11, vA11.y, aAy);
                aBx = fmaf(wB00, vB00.x, aBx); aBy = fmaf(wB00, vB00.y, aBy);
                aBx = fmaf(wB01, vB01.x, aBx); aBy = fmaf(wB01, vB01.y, aBy);
                aBx = fmaf(wB10, vB10.x, aBx); aBy = fmaf(wB10, vB10.y, aBy);
                aBx = fmaf(wB11, vB11.x, aBx); aBy = fmaf(wB11, vB11.y, aBy);
            }
            st[pixA * (X1S / 2) + gA * (GC_ / 2) + k] = make_float2(aAx, aAy);
            st[pixB * (X1S / 2) + gB * (GC_ / 2) + k] = make_float2(aBx, aBy);
        }
    }
    __syncthreads();
    {
        const int pix = t & 15;
        const int cq  = t >> 4;
        #pragma unroll
        for (int i = 0; i < 8; ++i) {
            const int c = cq * 8 + i;
            out[(((size_t)n * C_ + c) * H_ + h) * W_ + w0 + pix] = x1[pix * X1S + c];
        }
    }
}

extern "C" void kernel_launch(void* const* d_in, const int* in_sizes, int n_in,
                              void* d_out, int out_size, void* d_ws, size_t ws_size,
                              hipStream_t stream) {
    const float* inp  = (const float*)d_in[0];
    const float* xin  = (const float*)d_in[1];
    const float* dww  = (const float*)d_in[2];
    const float* dwb  = (const float*)d_in[3];
    const float* lng  = (const float*)d_in[4];
    const float* lnb  = (const float*)d_in[5];
    const float* offw = (const float*)d_in[6];
    const float* offb = (const float*)d_in[7];
    float* outp = (float*)d_out;

    const int blocks = N_ * H_ * (W_ / WT);   // 2048

    if (ws_size >= DESC_BYTES) {
        uint4* desc = (uint4*)d_ws;
        dcn_stage1<<<dim3(blocks), dim3(256), 0, stream>>>(
            inp, dww, dwb, lng, lnb, offw, offb, desc);
        dcn_gather<<<dim3(blocks), dim3(512), 0, stream>>>(xin, desc, outp);
    } else {
        dcn_fused_mono<<<dim3(blocks), dim3(256), 0, stream>>>(
            inp, xin, dww, dwb, lng, lnb, offw, offb, outp);
    }
}